// Round 17
// baseline (306.337 us; speedup 1.0000x reference)
//
#include <hip/hip_runtime.h>
#include <hip/hip_bf16.h>
#include <math.h>

#define B_   4
#define CIN  64
#define P_   1728
#define N_   1729
#define C_   256
#define NH_  8
#define HD_  32
#define M_   (B_*N_)   // 6916 rows
#define NPAD 1792      // 28 * 64

typedef __bf16 bf16x8 __attribute__((ext_vector_type(8)));
typedef __bf16 bf16x4 __attribute__((ext_vector_type(4)));
typedef float  f32x4  __attribute__((ext_vector_type(4)));

// ---------------------------------------------------------------------------
// Patch embed. One thread per (b, n, c). Writes t fp32.
// ---------------------------------------------------------------------------
__global__ __launch_bounds__(256) void embed2(
    const float* __restrict__ x, const float* __restrict__ Wpe,
    const float* __restrict__ bpe, const float* __restrict__ cls,
    float* __restrict__ t)
{
    int idx = blockIdx.x*256 + threadIdx.x;        // [0, B*N*C)
    int c   = idx & 255;
    int n   = (idx >> 8) % N_;
    int b   = idx / (N_*256);
    if (n == 0) { t[idx] = cls[c]; return; }
    int p = n - 1;
    float acc = bpe[c];
    for (int ci = 0; ci < CIN; ++ci)
        acc += x[(size_t)(b*CIN + ci)*P_ + p] * Wpe[ci*C_ + c];
    t[idx] = acc;
}

// ---------------------------------------------------------------------------
// ln4: LayerNorm, 4 rows/block (one wave each), float4 in, bf16x4 out.
// ---------------------------------------------------------------------------
__global__ __launch_bounds__(256) void ln4(
    const float* __restrict__ in, __bf16* __restrict__ out,
    const float* __restrict__ g, const float* __restrict__ bb)
{
    int wv = threadIdx.x >> 6, lane = threadIdx.x & 63;
    size_t row = (size_t)blockIdx.x*4 + wv;
    float4 v = *(const float4*)&in[row*C_ + lane*4];
    float s1 = (v.x+v.y)+(v.z+v.w);
    float s2 = (v.x*v.x+v.y*v.y)+(v.z*v.z+v.w*v.w);
    #pragma unroll
    for (int off = 32; off >= 1; off >>= 1) {
        s1 += __shfl_xor(s1, off);
        s2 += __shfl_xor(s2, off);
    }
    float mean = s1*(1.0f/C_);
    float var  = fmaxf(s2*(1.0f/C_) - mean*mean, 0.0f);
    float rstd = rsqrtf(var + 1e-5f);
    float4 gg = *(const float4*)&g[lane*4];
    float4 bv = *(const float4*)&bb[lane*4];
    bf16x4 r;
    r[0] = (__bf16)((v.x-mean)*rstd*gg.x + bv.x);
    r[1] = (__bf16)((v.y-mean)*rstd*gg.y + bv.y);
    r[2] = (__bf16)((v.z-mean)*rstd*gg.z + bv.z);
    r[3] = (__bf16)((v.w-mean)*rstd*gg.w + bv.w);
    *(bf16x4*)&out[row*C_ + lane*4] = r;
}

// ln4f: final norm — fp32 out + cls extraction.
__global__ __launch_bounds__(256) void ln4f(
    const float* __restrict__ in, float* __restrict__ out,
    const float* __restrict__ g, const float* __restrict__ bb,
    float* __restrict__ cls_out)
{
    int wv = threadIdx.x >> 6, lane = threadIdx.x & 63;
    size_t row = (size_t)blockIdx.x*4 + wv;
    float4 v = *(const float4*)&in[row*C_ + lane*4];
    float s1 = (v.x+v.y)+(v.z+v.w);
    float s2 = (v.x*v.x+v.y*v.y)+(v.z*v.z+v.w*v.w);
    #pragma unroll
    for (int off = 32; off >= 1; off >>= 1) {
        s1 += __shfl_xor(s1, off);
        s2 += __shfl_xor(s2, off);
    }
    float mean = s1*(1.0f/C_);
    float var  = fmaxf(s2*(1.0f/C_) - mean*mean, 0.0f);
    float rstd = rsqrtf(var + 1e-5f);
    float4 gg = *(const float4*)&g[lane*4];
    float4 bv = *(const float4*)&bb[lane*4];
    float4 r;
    r.x = (v.x-mean)*rstd*gg.x + bv.x;
    r.y = (v.y-mean)*rstd*gg.y + bv.y;
    r.z = (v.z-mean)*rstd*gg.z + bv.z;
    r.w = (v.w-mean)*rstd*gg.w + bv.w;
    *(float4*)&out[row*C_ + lane*4] = r;
    if ((row % N_) == 0)
        *(float4*)&cls_out[(row / N_)*C_ + lane*4] = r;
}

// ---------------------------------------------------------------------------
// wprep2: all 8 weight matrices -> bf16 W^T[n][k] in one launch.
// ---------------------------------------------------------------------------
__global__ __launch_bounds__(256) void wprep2(
    const float* __restrict__ Wqkv, const float* __restrict__ Wproj,
    const float* __restrict__ W1,   const float* __restrict__ W2,
    __bf16* __restrict__ wT)
{
    int z = blockIdx.z, which = z >> 1, layer = z & 1;
    const float* src; __bf16* dst; int NC;
    if (which == 0) {
        src = Wqkv + (size_t)layer*C_*768;
        dst = wT   + (size_t)layer*768*256;
        NC  = 768;
    } else {
        NC = 256;
        const float* b3 = (which == 1) ? Wproj : (which == 2) ? W1 : W2;
        src = b3 + (size_t)layer*65536;
        dst = wT + 2*768*256 + (size_t)((which-1)*2 + layer)*65536;
    }
    int n0 = blockIdx.x*32; if (n0 >= NC) return;
    int k0 = blockIdx.y*32;
    __shared__ float tile[32][33];
    int c = threadIdx.x & 31, r = threadIdx.x >> 5;
    for (int rr = r; rr < 32; rr += 8)
        tile[rr][c] = src[(size_t)(k0+rr)*NC + n0 + c];
    __syncthreads();
    for (int rr = r; rr < 32; rr += 8)
        dst[(size_t)(n0+rr)*256 + k0 + c] = (__bf16)tile[c][rr];
}

// ---------------------------------------------------------------------------
// padzero: zero kB/vB pad rows (n in [N_, NPAD)) so attention needs no
// masking: pad keys add exp2(0)=1 to l (subtracted in combine) and 0 to O.
// ---------------------------------------------------------------------------
__global__ __launch_bounds__(256) void padzero(
    __bf16* __restrict__ kB, __bf16* __restrict__ vB)
{
    int idx = blockIdx.x*256 + threadIdx.x;     // over 32*63*32 = 64512
    if (idx >= 32*63*32) return;
    int d  = idx & 31;
    int n  = (idx >> 5) % 63 + N_;
    int bh = idx / (63*32);
    kB[((size_t)bh*NPAD + n)*32 + d] = (__bf16)0.f;
    vB[((size_t)bh*32 + d)*NPAD + n] = (__bf16)0.f;
}

// ---------------------------------------------------------------------------
// gemm3: out[M,NC] (+)= A[M,256](bf16) @ WtT (+bias fp32)(gelu). 64x64 tile,
// BK=64 (4 k-iters), XOR-swizzled dense LDS (chunk c at c^(row&7)).
// ---------------------------------------------------------------------------
template<int NC, bool ADD, bool GELU, bool BIAS, bool OUTBF>
__global__ __launch_bounds__(256) void gemm3(
    const __bf16* __restrict__ A, const __bf16* __restrict__ Wt,
    const float* __restrict__ bias, float* __restrict__ outF,
    __bf16* __restrict__ outB)
{
    __shared__ __align__(16) __bf16 As[64*64];
    __shared__ __align__(16) __bf16 Bs[64*64];
    int r0 = blockIdx.x*64, c0 = blockIdx.y*64;
    int tid = threadIdx.x;
    int wv = tid >> 6, lane = tid & 63, quad = lane >> 4, mn = lane & 15;
    int sr = tid >> 2, sc = tid & 3;
    int ga = r0 + sr; if (ga >= M_) ga = M_ - 1;

    f32x4 acc[4];
    #pragma unroll
    for (int ct = 0; ct < 4; ++ct)
        #pragma unroll
        for (int rr = 0; rr < 4; ++rr) acc[ct][rr] = 0.f;

    for (int kc = 0; kc < 4; ++kc) {
        __syncthreads();
        *(bf16x8*)&As[sr*64 + ((sc ^ (sr & 7))*8)] =
            *(const bf16x8*)&A[(size_t)ga*256 + kc*64 + sc*8];
        *(bf16x8*)&As[sr*64 + (((sc+4) ^ (sr & 7))*8)] =
            *(const bf16x8*)&A[(size_t)ga*256 + kc*64 + sc*8 + 32];
        *(bf16x8*)&Bs[sr*64 + ((sc ^ (sr & 7))*8)] =
            *(const bf16x8*)&Wt[(size_t)(c0+sr)*256 + kc*64 + sc*8];
        *(bf16x8*)&Bs[sr*64 + (((sc+4) ^ (sr & 7))*8)] =
            *(const bf16x8*)&Wt[(size_t)(c0+sr)*256 + kc*64 + sc*8 + 32];
        __syncthreads();

        #pragma unroll
        for (int h = 0; h < 2; ++h) {
            bf16x8 a = *(const bf16x8*)&As[(wv*16 + mn)*64 + (((h*4+quad) ^ (mn & 7))*8)];
            #pragma unroll
            for (int ct = 0; ct < 4; ++ct) {
                bf16x8 b = *(const bf16x8*)&Bs[(ct*16 + mn)*64 + (((h*4+quad) ^ (mn & 7))*8)];
                acc[ct] = __builtin_amdgcn_mfma_f32_16x16x32_bf16(a, b, acc[ct], 0, 0, 0);
            }
        }
    }

    #pragma unroll
    for (int ct = 0; ct < 4; ++ct) {
        int col = c0 + ct*16 + mn;
        #pragma unroll
        for (int rr = 0; rr < 4; ++rr) {
            int row = r0 + wv*16 + quad*4 + rr;
            if (row >= M_) continue;
            float val = acc[ct][rr];
            if (BIAS) val += bias[col];
            if (GELU) val = 0.5f*val*(1.f + erff(val*0.70710678118654752f));
            size_t oi = (size_t)row*NC + col;
            if (OUTBF) outB[oi] = (__bf16)val;
            else if (ADD) outF[oi] += val;
            else outF[oi] = val;
        }
    }
}

// ---------------------------------------------------------------------------
// gemm_qkv3: BK=64 core; epilogue packs qB (scaled by 1/sqrt(32)*log2(e) so
// attention can use raw exp2), kB, vB (transposed).
// ---------------------------------------------------------------------------
__global__ __launch_bounds__(256) void gemm_qkv3(
    const __bf16* __restrict__ A, const __bf16* __restrict__ Wt,
    __bf16* __restrict__ qB, __bf16* __restrict__ kB, __bf16* __restrict__ vB)
{
    __shared__ __align__(16) __bf16 As[64*64];
    __shared__ __align__(16) __bf16 Bs[64*64];
    int r0 = blockIdx.x*64, c0 = blockIdx.y*64;
    int tid = threadIdx.x;
    int wv = tid >> 6, lane = tid & 63, quad = lane >> 4, mn = lane & 15;
    int sr = tid >> 2, sc = tid & 3;
    int ga = r0 + sr; if (ga >= M_) ga = M_ - 1;

    f32x4 acc[4];
    #pragma unroll
    for (int ct = 0; ct < 4; ++ct)
        #pragma unroll
        for (int rr = 0; rr < 4; ++rr) acc[ct][rr] = 0.f;

    for (int kc = 0; kc < 4; ++kc) {
        __syncthreads();
        *(bf16x8*)&As[sr*64 + ((sc ^ (sr & 7))*8)] =
            *(const bf16x8*)&A[(size_t)ga*256 + kc*64 + sc*8];
        *(bf16x8*)&As[sr*64 + (((sc+4) ^ (sr & 7))*8)] =
            *(const bf16x8*)&A[(size_t)ga*256 + kc*64 + sc*8 + 32];
        *(bf16x8*)&Bs[sr*64 + ((sc ^ (sr & 7))*8)] =
            *(const bf16x8*)&Wt[(size_t)(c0+sr)*256 + kc*64 + sc*8];
        *(bf16x8*)&Bs[sr*64 + (((sc+4) ^ (sr & 7))*8)] =
            *(const bf16x8*)&Wt[(size_t)(c0+sr)*256 + kc*64 + sc*8 + 32];
        __syncthreads();

        #pragma unroll
        for (int h = 0; h < 2; ++h) {
            bf16x8 a = *(const bf16x8*)&As[(wv*16 + mn)*64 + (((h*4+quad) ^ (mn & 7))*8)];
            #pragma unroll
            for (int ct = 0; ct < 4; ++ct) {
                bf16x8 b = *(const bf16x8*)&Bs[(ct*16 + mn)*64 + (((h*4+quad) ^ (mn & 7))*8)];
                acc[ct] = __builtin_amdgcn_mfma_f32_16x16x32_bf16(a, b, acc[ct], 0, 0, 0);
            }
        }
    }

    const float scale = 0.25503473109f;   // (1/sqrt(32)) * log2(e)
    #pragma unroll
    for (int ct = 0; ct < 4; ++ct) {
        int col = c0 + ct*16 + mn;
        #pragma unroll
        for (int rr = 0; rr < 4; ++rr) {
            int row = r0 + wv*16 + quad*4 + rr;
            if (row >= M_) continue;
            int b = row / N_, n = row - b*N_;
            float val = acc[ct][rr];
            if (col < 256) {
                int h = col >> 5, dd = col & 31;
                qB[((size_t)(b*NH_+h)*NPAD + n)*32 + dd] = (__bf16)(val*scale);
            } else if (col < 512) {
                int h = (col-256) >> 5, dd = col & 31;
                kB[((size_t)(b*NH_+h)*NPAD + n)*32 + dd] = (__bf16)val;
            } else {
                int h = (col-512) >> 5, dd = col & 31;
                vB[((size_t)(b*NH_+h)*32 + dd)*NPAD + n] = (__bf16)val;
            }
        }
    }
}

// ---------------------------------------------------------------------------
// attn12: key-split flash attention. Grid (bh, qtile, half): each block sums
// 896 keys (7 x 128-key tiles), emitting UNNORMALIZED partial O (bf16) and
// partial l (fp32). exp2 (scale pre-folded). Pad keys (half 1) add 1 to l.
// ---------------------------------------------------------------------------
__global__ __launch_bounds__(256) void attn12(
    const __bf16* __restrict__ qB, const __bf16* __restrict__ kB,
    const __bf16* __restrict__ vB, __bf16* __restrict__ oP,
    float* __restrict__ lP)
{
    int bh = blockIdx.x;
    int q0 = blockIdx.y * 64;
    int half = blockIdx.z;
    int tid = threadIdx.x;
    int wv = tid >> 6, lane = tid & 63, quad = lane >> 4, mn = lane & 15;

    __shared__ __align__(16) __bf16 lk[128*32];    // [key][d] swizzled
    __shared__ __align__(16) __bf16 lvt[32*128];   // [d][key] swizzled
    __shared__ __align__(16) __bf16 lp[4][16*72];  // per-wave P [q][key], stride 72

    bf16x8 qfrag = *(const bf16x8*)(
        qB + ((size_t)bh*NPAD + q0 + wv*16 + mn)*32 + quad*8);

    f32x4 oacc0, oacc1;
    #pragma unroll
    for (int rr = 0; rr < 4; ++rr) { oacc0[rr]=0.f; oacc1[rr]=0.f; }
    float lsum = 0.f;

    const __bf16* kbase = kB + (size_t)bh*NPAD*32;
    const __bf16* vbase = vB + (size_t)bh*32*NPAD;
    int sr = tid >> 2, sc = tid & 3;     // K staging rows/chunks
    int vr = tid >> 3, vc = tid & 7;     // V^T staging rows/chunks

    for (int t = 0; t < 7; ++t) {
        int k0 = half*896 + t*128;
        __syncthreads();
        #pragma unroll
        for (int hh = 0; hh < 2; ++hh) {
            int r = hh*64 + sr;
            *(bf16x8*)&lk[r*32 + ((sc ^ (r & 3))*8)] =
                *(const bf16x8*)(kbase + (size_t)(k0 + r)*32 + sc*8);
            int cp = hh*8 + vc;
            *(bf16x8*)&lvt[vr*128 + ((cp ^ (vr & 7))*8)] =
                *(const bf16x8*)(vbase + (size_t)vr*NPAD + k0 + cp*8);
        }
        __syncthreads();

        #pragma unroll
        for (int h2 = 0; h2 < 2; ++h2) {
            // S^T: A = K rows, B = Q -> lane holds P[key=ct*16+quad*4+rr][q=mn]
            #pragma unroll
            for (int ct = 0; ct < 4; ++ct) {
                int kr = h2*64 + ct*16 + mn;                 // kr&3 == mn&3
                bf16x8 kf = *(const bf16x8*)&lk[kr*32 + ((quad ^ (mn & 3))*8)];
                f32x4 z;
                #pragma unroll
                for (int rr = 0; rr < 4; ++rr) z[rr] = 0.f;
                f32x4 st = __builtin_amdgcn_mfma_f32_16x16x32_bf16(kf, qfrag, z, 0, 0, 0);

                bf16x4 pf4;
                #pragma unroll
                for (int rr = 0; rr < 4; ++rr) {
                    float p = exp2f(st[rr]);
                    pf4[rr] = (__bf16)p;
                    lsum += p;
                }
                *(bf16x4*)&lp[wv][mn*72 + ct*16 + quad*4] = pf4;
            }

            // O += P V
            #pragma unroll
            for (int kh = 0; kh < 2; ++kh) {
                bf16x8 pf = *(const bf16x8*)&lp[wv][mn*72 + kh*32 + quad*8];
                int chunk = h2*8 + kh*4 + quad;
                int vsw = (chunk ^ (mn & 7)) * 8;
                bf16x8 v0 = *(const bf16x8*)&lvt[ mn      *128 + vsw];
                bf16x8 v1 = *(const bf16x8*)&lvt[(mn+16)*128 + vsw];
                oacc0 = __builtin_amdgcn_mfma_f32_16x16x32_bf16(pf, v0, oacc0, 0, 0, 0);
                oacc1 = __builtin_amdgcn_mfma_f32_16x16x32_bf16(pf, v1, oacc1, 0, 0, 0);
            }
        }
    }

    // partial l(q=mn): reduce over quads; store raw (pad handled in combine)
    lsum += __shfl_xor(lsum, 16);
    lsum += __shfl_xor(lsum, 32);
    if (quad == 0)
        lP[((size_t)(half*32 + bh))*NPAD + q0 + wv*16 + mn] = lsum;

    // partial O (unnormalized, bf16)
    #pragma unroll
    for (int rr = 0; rr < 4; ++rr) {
        int q = q0 + wv*16 + quad*4 + rr;
        size_t base = (((size_t)(half*32 + bh))*NPAD + q)*32;
        oP[base + mn]      = (__bf16)oacc0[rr];
        oP[base + 16 + mn] = (__bf16)oacc1[rr];
    }
}

// ---------------------------------------------------------------------------
// attn_comb: o[b,n,h*32+d] = (O0 + O1) / (l0 + l1 - 63).  grid 1792 x 256.
// ---------------------------------------------------------------------------
__global__ __launch_bounds__(256) void attn_comb(
    const __bf16* __restrict__ oP, const float* __restrict__ lP,
    __bf16* __restrict__ o)
{
    int idx = blockIdx.x*256 + threadIdx.x;    // [0, 32*1792*8)
    int d4 = idx & 7;
    int q  = (idx >> 3) % NPAD;
    int bh = idx / (NPAD*8);
    if (q >= N_) return;
    int b = bh >> 3, h = bh & 7;
    float l = lP[(size_t)bh*NPAD + q] + lP[((size_t)(32 + bh))*NPAD + q] - 63.0f;
    float inv = 1.0f / l;
    bf16x4 o1 = *(const bf16x4*)&oP[(((size_t)bh)*NPAD + q)*32 + d4*4];
    bf16x4 o2 = *(const bf16x4*)&oP[(((size_t)(32 + bh))*NPAD + q)*32 + d4*4];
    bf16x4 r;
    #pragma unroll
    for (int j = 0; j < 4; ++j)
        r[j] = (__bf16)(((float)o1[j] + (float)o2[j]) * inv);
    *(bf16x4*)&o[((size_t)(b*N_ + q))*C_ + h*HD_ + d4*4] = r;
}

// ---------------------------------------------------------------------------
// feat3: LDS 32x32 tile transpose (fp32). grid (54, 8, 4).
// ---------------------------------------------------------------------------
__global__ __launch_bounds__(256) void feat3(
    const float* __restrict__ y, float* __restrict__ outf)
{
    __shared__ float tl[32][33];
    int p0 = blockIdx.x*32, c0 = blockIdx.y*32, b = blockIdx.z;
    int cc = threadIdx.x & 31, rr = threadIdx.x >> 5;
    for (int i = rr; i < 32; i += 8)
        tl[i][cc] = y[((size_t)(b*N_) + 1 + p0 + i)*C_ + c0 + cc];
    __syncthreads();
    for (int i = rr; i < 32; i += 8)
        outf[((size_t)(b*C_) + c0 + i)*P_ + p0 + cc] = tl[cc][i];
}

// ---------------------------------------------------------------------------
extern "C" void kernel_launch(void* const* d_in, const int* in_sizes, int n_in,
                              void* d_out, int out_size, void* d_ws, size_t ws_size,
                              hipStream_t stream)
{
    const float* x        = (const float*)d_in[0];
    const float* W_pe     = (const float*)d_in[1];
    const float* b_pe     = (const float*)d_in[2];
    const float* cls_tok  = (const float*)d_in[3];
    const float* ln1_g    = (const float*)d_in[4];
    const float* ln1_b    = (const float*)d_in[5];
    const float* Wqkv     = (const float*)d_in[6];
    const float* Wproj    = (const float*)d_in[7];
    const float* bproj    = (const float*)d_in[8];
    const float* ln2_g    = (const float*)d_in[9];
    const float* ln2_b    = (const float*)d_in[10];
    const float* W1       = (const float*)d_in[11];
    const float* b1       = (const float*)d_in[12];
    const float* W2       = (const float*)d_in[13];
    const float* b2       = (const float*)d_in[14];
    const float* normf_g  = (const float*)d_in[15];
    const float* normf_b  = (const float*)d_in[16];

    const size_t MC = (size_t)M_*C_;    // 1,770,496
    float*  ws  = (float*)d_ws;
    float*  t   = ws;                               // MC fp32
    float*  yf  = ws + MC;                          // MC fp32 (final ln out)
    __bf16* ybf = (__bf16*)(ws + 2*MC);             // MC bf16
    __bf16* hbf = (__bf16*)(ws + 2*MC + MC/2);      // MC bf16
    __bf16* obf = (__bf16*)(ws + 2*MC + MC);        // MC bf16
    __bf16* wT  = (__bf16*)(ws + 2*MC + 3*(MC/2));  // 786432 bf16
    __bf16* qB  = wT + 2*768*256 + 6*256*256;       // [32][NPAD][32]
    __bf16* kB  = qB + (size_t)B_*NH_*NPAD*32;
    __bf16* vB  = kB + (size_t)B_*NH_*NPAD*32;      // [32][32][NPAD]
    __bf16* oP  = vB + (size_t)B_*NH_*NPAD*32;      // [2][32][NPAD][32] bf16
    float*  lP  = (float*)(oP + (size_t)2*B_*NH_*NPAD*32);  // [2][32][NPAD] fp32

    __bf16* projT = wT + 2*768*256;
    __bf16* w1T   = projT + 2*256*256;
    __bf16* w2T   = w1T   + 2*256*256;

    float* out_cls  = (float*)d_out;
    float* out_feat = out_cls + B_*C_;

    wprep2<<<dim3(24, 8, 8), 256, 0, stream>>>(Wqkv, Wproj, W1, W2, wT);
    padzero<<<252, 256, 0, stream>>>(kB, vB);
    embed2<<<(B_*N_*C_)/256, 256, 0, stream>>>(x, W_pe, b_pe, cls_tok, t);

    const int GRID_M = (M_ + 63) / 64;   // 109
    for (int i = 0; i < 2; ++i) {
        ln4<<<M_/4, 256, 0, stream>>>(t, ybf, ln1_g + i*C_, ln1_b + i*C_);
        gemm_qkv3<<<dim3(GRID_M, 12), 256, 0, stream>>>(
            ybf, wT + (size_t)i*768*256, qB, kB, vB);
        attn12<<<dim3(32, 28, 2), 256, 0, stream>>>(qB, kB, vB, oP, lP);
        attn_comb<<<(32*NPAD*8)/256, 256, 0, stream>>>(oP, lP, obf);
        gemm3<256,true,false,true,false><<<dim3(GRID_M, 4), 256, 0, stream>>>(
            obf, projT + (size_t)i*65536, bproj + i*C_, t, nullptr);
        ln4<<<M_/4, 256, 0, stream>>>(t, ybf, ln2_g + i*C_, ln2_b + i*C_);
        gemm3<256,false,true,true,true><<<dim3(GRID_M, 4), 256, 0, stream>>>(
            ybf, w1T + (size_t)i*65536, b1 + i*C_, nullptr, hbf);
        gemm3<256,true,false,true,false><<<dim3(GRID_M, 4), 256, 0, stream>>>(
            hbf, w2T + (size_t)i*65536, b2 + i*C_, t, nullptr);
    }

    ln4f<<<M_/4, 256, 0, stream>>>(t, yf, normf_g, normf_b, out_cls);
    feat3<<<dim3(54, 8, 4), 256, 0, stream>>>(yf, out_feat);
}